// Round 18
// baseline (100.465 us; speedup 1.0000x reference)
//
#include <hip/hip_runtime.h>
#include <math.h>

#define DET 512
#define NA  180
#define OUT 362   // floor(sqrt(512^2/2))
#define RAD 181   // OUT/2
#define OUTSQ (OUT * OUT)

#define NSPLIT 6        // angle partitions per (pair-group, tile)
#define APB    30       // angles per block (NA / NSPLIT)
#define CHUNK  6        // pair-lines staged per barrier round (24.7 KB LDS)
#define NR     (APB / CHUNK)   // 5 staging rounds
#define LSTR2  1028     // floats per staged pair-line (512*2 data + sentinels)
#define QPR    (CHUNK * DET * 2 / 4)   // 1536 quads per round

// ---------------------------------------------------------------------------
// ft scratch in a static device global (R15: −1.4 us vs binding d_ws).
// g_ft is fully rewritten by ramp_filter before backproject reads it each
// iteration — no cross-iteration semantic state.
// ---------------------------------------------------------------------------
__device__ float g_ft[2 * NA * DET * 2];   // pair-interleaved, 1.47 MB

// ---------------------------------------------------------------------------
// Compile-time tables / weights.
// ---------------------------------------------------------------------------
constexpr double PI_D = 3.14159265358979323846;

constexpr double tsin(double x) {  // |x| <= pi/4
    double x2 = x * x;
    return x * (1.0 + x2 * (-1.0/6 + x2 * (1.0/120 + x2 * (-1.0/5040 +
               x2 * (1.0/362880 + x2 * (-1.0/39916800))))));
}
constexpr double tcos(double x) {  // |x| <= pi/4
    double x2 = x * x;
    return 1.0 + x2 * (-0.5 + x2 * (1.0/24 + x2 * (-1.0/720 +
               x2 * (1.0/40320 + x2 * (-1.0/3628800)))));
}

struct Trig { float c[NA]; float s[NA]; };
constexpr Trig make_trig() {
    Trig t{};
    constexpr double r = PI_D / 180.0;
    for (int k = 0; k < NA; ++k) {
        double c, s;
        if (k <= 45)       { c =  tcos(k * r);          s =  tsin(k * r); }
        else if (k <= 90)  { c =  tsin((90 - k) * r);   s =  tcos((90 - k) * r); }
        else if (k <= 135) { c = -tsin((k - 90) * r);   s =  tcos((k - 90) * r); }
        else               { c = -tcos((180 - k) * r);  s =  tsin((180 - k) * r); }
        t.c[k] = (float)c; t.s[k] = (float)s;
    }
    return t;
}
__device__ constexpr Trig TRIG = make_trig();

// Ramp weight for odd offset m: w(m) = -2/(pi*m)^2; 0 outside [-511,511] or
// even m.  ONLY used in constexpr context so it folds to a 32-bit literal
// (R4 lesson: runtime eval = f64 VALU storm, 90 us).
__host__ __device__ constexpr float rampw0(int m) {
    int a = m < 0 ? -m : m;
    if (a > 511 || (a & 1) == 0) return 0.0f;
    double md = (double)a;
    return (float)(-2.0 / (PI_D * PI_D * md * md));
}

// One tap: v = p[R] feeds the 4 accumulators with compile-time weights.
template<int R>
__device__ __forceinline__ void tap(const float* __restrict__ p,
        float& a0, float& a1, float& a2, float& a3) {
    const float v = p[R];
    if constexpr (rampw0(R)      != 0.0f) a0 = fmaf(rampw0(R),      v, a0);
    if constexpr (rampw0(R - 32) != 0.0f) a1 = fmaf(rampw0(R - 32), v, a1);
    if constexpr (rampw0(R - 64) != 0.0f) a2 = fmaf(rampw0(R - 64), v, a2);
    if constexpr (rampw0(R - 96) != 0.0f) a3 = fmaf(rampw0(R - 96), v, a3);
}

// Straight-line sweep over odd offsets R, R+2, ..., REND.
template<int R, int REND>
__device__ __forceinline__ void sweep(const float* __restrict__ p,
        float& a0, float& a1, float& a2, float& a3) {
    if constexpr (R <= REND) {
        tap<R>(p, a0, a1, a2, a3);
        sweep<R + 2, REND>(p, a0, a1, a2, a3);
    }
}

// ---------------------------------------------------------------------------
// Kernel 1: ramp filter — R5's proven structure, output pair-interleaved
// g_ft[g][a][d][2] (g = b>>1, j = b&1).
// ---------------------------------------------------------------------------
__global__ __launch_bounds__(256) void ramp_filter_kernel(
        const float* __restrict__ x) {
    const int a   = blockIdx.x;
    const int b   = blockIdx.y;
    const int tid = threadIdx.x;        // 0..255
    const int t    = tid & 127;         // output-thread id
    const int half = tid >> 7;          // window half
    const int q = (t & 31) + 128 * (t >> 5);   // base output (covers all 512)

    __shared__ float xs[3 * DET];       // [0,512) zeros | data | [1024,1536) zeros
    __shared__ float red[4 * 128];      // half-1 partial accumulators

    xs[tid]        = 0.0f;
    xs[256 + tid]  = 0.0f;
    xs[1024 + tid] = 0.0f;
    xs[1280 + tid] = 0.0f;
    xs[512 + tid]  = x[(b * DET + tid) * NA + a];
    xs[768 + tid]  = x[(b * DET + 256 + tid) * NA + a];
    __syncthreads();

    const float* p = xs + 512 + q;
    float a0 = 0.0f, a1 = 0.0f, a2 = 0.0f, a3 = 0.0f;

    if (half == 0) {
        a0 = 0.5f * p[0];               // center taps, once
        a1 = 0.5f * p[32];
        a2 = 0.5f * p[64];
        a3 = 0.5f * p[96];
        sweep<-511, 47>(p, a0, a1, a2, a3);
    } else {
        sweep<49, 607>(p, a0, a1, a2, a3);
        red[      t] = a0;
        red[128 + t] = a1;
        red[256 + t] = a2;
        red[384 + t] = a3;
    }
    __syncthreads();

    if (half == 0) {
        const int g = b >> 1, j = b & 1;
        float* o = g_ft + (((size_t)g * NA + a) * DET + q) * 2 + j;
        o[0]       = a0 + red[      t];
        o[32 * 2]  = a1 + red[128 + t];
        o[64 * 2]  = a2 + red[256 + t];
        o[96 * 2]  = a3 + red[384 + t];
    }
}

// ---------------------------------------------------------------------------
// Kernel 2: backprojection — R16's proven form (pair-fused + T14 async
// stage, single LDS buffer) with CHUNK 3->6: 5 staging rounds instead of
// 10, halving barrier convoys and vmcnt re-exposure windows.  R17's dbuf
// regressed (+1.4 us: extra LDS + merged-phase lgkmcnt coupling); this
// keeps R16's exact phase order.
// ---------------------------------------------------------------------------
__device__ __forceinline__ void interp2(float2& acc,
        const float* __restrict__ L, float pos) {
    float pf = floorf(pos);
    int   i0 = (int)pf;
    float fr = pos - pf;
    const float* qp = L + 2 * i0;
    float g00 = qp[0], g01 = qp[1];          // pair at d = i0
    float g10 = qp[2], g11 = qp[3];          // pair at d = i0+1
    float v0 = fmaf(fr, g10 - g00, g00);
    float v1 = fmaf(fr, g11 - g01, g01);
    bool in = pos <= (float)(DET - 1);       // fill=0 outside
    acc.x += in ? v0 : 0.0f;
    acc.y += in ? v1 : 0.0f;
}

__global__ __launch_bounds__(256) void backproject_kernel(
        float* __restrict__ out) {
    const int bz = blockIdx.z;
    const int g  = bz / NSPLIT;              // image pair 0..1
    const int sp = bz - g * NSPLIT;
    const int r0 = blockIdx.y * 32;
    const int c0 = blockIdx.x * 32;
    const int tid = threadIdx.x;
    const int tx = tid & 15;
    const int ty = tid >> 4;

    __shared__ float line[CHUNK * LSTR2];    // 6 pair-lines, 24.7 KB

    // zero sentinel pair at d=512 (dwords 1024,1025 of each line)
    if (tid < 2 * CHUNK)
        line[(tid >> 1) * LSTR2 + 1024 + (tid & 1)] = 0.0f;

    // clamp base coordinate for guard pixels (r/c >= OUT); stores guarded.
    const float xpr = (float)(min(r0 + ty, OUT - 1) - RAD);   // row coord
    const float ypr = (float)(min(c0 + tx, OUT - 1) - RAD);   // col coord

    float2 a00 = {0,0}, a01 = {0,0}, a10 = {0,0}, a11 = {0,0};

    const float4* base4 =
        (const float4*)(g_ft + ((size_t)g * NA + sp * APB) * DET * 2);
    const int dq = tid << 2;                 // dword offset within a line

    // prologue: prefetch chunk 0 (6 quads/thread; quad tid+256k -> line k,
    // dword tid<<2)
    float4 pf0 = base4[tid];
    float4 pf1 = base4[tid + 256];
    float4 pf2 = base4[tid + 512];
    float4 pf3 = base4[tid + 768];
    float4 pf4 = base4[tid + 1024];
    float4 pf5 = base4[tid + 1280];

    for (int rd = 0; rd < NR; ++rd) {
        __syncthreads();                     // previous round's compute done
        *(float4*)&line[0 * LSTR2 + dq] = pf0;   // waits vmcnt here
        *(float4*)&line[1 * LSTR2 + dq] = pf1;
        *(float4*)&line[2 * LSTR2 + dq] = pf2;
        *(float4*)&line[3 * LSTR2 + dq] = pf3;
        *(float4*)&line[4 * LSTR2 + dq] = pf4;
        *(float4*)&line[5 * LSTR2 + dq] = pf5;
        __syncthreads();

        // issue next round's loads NOW — latency hides under compute below
        if (rd + 1 < NR) {
            const float4* gn = base4 + (size_t)(rd + 1) * QPR;
            pf0 = gn[tid];        pf1 = gn[tid + 256];
            pf2 = gn[tid + 512];  pf3 = gn[tid + 768];
            pf4 = gn[tid + 1024]; pf5 = gn[tid + 1280];
        }

        const int abase = sp * APB + rd * CHUNK;
        #pragma unroll
        for (int i = 0; i < CHUNK; ++i) {
            const float cv = TRIG.c[abase + i];
            const float sv = TRIG.s[abase + i];
            // pos = ypr*cos - xpr*sin + det/2
            float p00 = fmaf(ypr, cv, fmaf(xpr, -sv, 256.0f));
            float p01 = fmaf(16.0f, cv, p00);       // col+16
            float p10 = fmaf(-16.0f, sv, p00);      // row+16
            float p11 = fmaf(-16.0f, sv, p01);      // row+16, col+16
            const float* L = line + i * LSTR2;
            interp2(a00, L, p00);
            interp2(a01, L, p01);
            interp2(a10, L, p10);
            interp2(a11, L, p11);
        }
    }

    const float scale = (float)(PI_D / (2.0 * NA));
    const int r = r0 + ty;
    const int c = c0 + tx;
    float* ob0 = out + (size_t)(2 * g)     * OUTSQ;
    float* ob1 = out + (size_t)(2 * g + 1) * OUTSQ;

#define EMIT(ACC, RR, CC)                                          \
    if ((RR) < OUT && (CC) < OUT) {                                \
        const int off = (RR) * OUT + (CC);                         \
        atomicAdd(ob0 + off, (ACC).x * scale);                     \
        atomicAdd(ob1 + off, (ACC).y * scale);                     \
    }
    EMIT(a00, r, c);
    EMIT(a01, r, c + 16);
    EMIT(a10, r + 16, c);
    EMIT(a11, r + 16, c + 16);
#undef EMIT
}

extern "C" void kernel_launch(void* const* d_in, const int* in_sizes, int n_in,
                              void* d_out, int out_size, void* d_ws, size_t ws_size,
                              hipStream_t stream) {
    const float* x = (const float*)d_in[0];
    float* out = (float*)d_out;

    const int B = in_sizes[0] / (DET * NA);   // 4 (fixed)
    (void)d_ws; (void)ws_size;                // workspace deliberately unused

    hipMemsetAsync(out, 0, (size_t)out_size * sizeof(float), stream);
    ramp_filter_kernel<<<dim3(NA, B), 256, 0, stream>>>(x);
    backproject_kernel<<<dim3((OUT + 31) / 32, (OUT + 31) / 32, (B / 2) * NSPLIT),
                         256, 0, stream>>>(out);
}

// Round 19
// 91.462 us; speedup vs baseline: 1.0984x; 1.0984x over previous
//
#include <hip/hip_runtime.h>
#include <math.h>

#define DET 512
#define NA  180
#define OUT 362   // floor(sqrt(512^2/2))
#define RAD 181   // OUT/2
#define OUTSQ (OUT * OUT)

#define NSPLIT 6        // angle partitions per (pair-group, tile)
#define APB    30       // angles per block (NA / NSPLIT)
#define CHUNK  3        // pair-lines staged per barrier (12.3 KB LDS)
#define LSTR2  1028     // floats per staged pair-line (512*2 data + sentinels)

// ---------------------------------------------------------------------------
// ft scratch in a static device global (R15 A/B: −1.4 us vs binding d_ws;
// the harness ws poison-fill is unconditional so it stays in the timed
// window either way).  g_ft is fully rewritten by ramp_filter before
// backproject reads it each iteration — no cross-iteration semantic state.
// ---------------------------------------------------------------------------
__device__ float g_ft[2 * NA * DET * 2];   // pair-interleaved, 1.47 MB

// ---------------------------------------------------------------------------
// Compile-time tables / weights.
// ---------------------------------------------------------------------------
constexpr double PI_D = 3.14159265358979323846;

constexpr double tsin(double x) {  // |x| <= pi/4
    double x2 = x * x;
    return x * (1.0 + x2 * (-1.0/6 + x2 * (1.0/120 + x2 * (-1.0/5040 +
               x2 * (1.0/362880 + x2 * (-1.0/39916800))))));
}
constexpr double tcos(double x) {  // |x| <= pi/4
    double x2 = x * x;
    return 1.0 + x2 * (-0.5 + x2 * (1.0/24 + x2 * (-1.0/720 +
               x2 * (1.0/40320 + x2 * (-1.0/3628800)))));
}

struct Trig { float c[NA]; float s[NA]; };
constexpr Trig make_trig() {
    Trig t{};
    constexpr double r = PI_D / 180.0;
    for (int k = 0; k < NA; ++k) {
        double c, s;
        if (k <= 45)       { c =  tcos(k * r);          s =  tsin(k * r); }
        else if (k <= 90)  { c =  tsin((90 - k) * r);   s =  tcos((90 - k) * r); }
        else if (k <= 135) { c = -tsin((k - 90) * r);   s =  tcos((k - 90) * r); }
        else               { c = -tcos((180 - k) * r);  s =  tsin((180 - k) * r); }
        t.c[k] = (float)c; t.s[k] = (float)s;
    }
    return t;
}
__device__ constexpr Trig TRIG = make_trig();

// Ramp weight for odd offset m: w(m) = -2/(pi*m)^2; 0 outside [-511,511] or
// even m.  ONLY used in constexpr context so it folds to a 32-bit literal
// (R4 lesson: runtime eval = f64 VALU storm, 90 us).
__host__ __device__ constexpr float rampw0(int m) {
    int a = m < 0 ? -m : m;
    if (a > 511 || (a & 1) == 0) return 0.0f;
    double md = (double)a;
    return (float)(-2.0 / (PI_D * PI_D * md * md));
}

// One tap: v = p[R] feeds the 4 accumulators with compile-time weights.
template<int R>
__device__ __forceinline__ void tap(const float* __restrict__ p,
        float& a0, float& a1, float& a2, float& a3) {
    const float v = p[R];
    if constexpr (rampw0(R)      != 0.0f) a0 = fmaf(rampw0(R),      v, a0);
    if constexpr (rampw0(R - 32) != 0.0f) a1 = fmaf(rampw0(R - 32), v, a1);
    if constexpr (rampw0(R - 64) != 0.0f) a2 = fmaf(rampw0(R - 64), v, a2);
    if constexpr (rampw0(R - 96) != 0.0f) a3 = fmaf(rampw0(R - 96), v, a3);
}

// Straight-line sweep over odd offsets R, R+2, ..., REND.
template<int R, int REND>
__device__ __forceinline__ void sweep(const float* __restrict__ p,
        float& a0, float& a1, float& a2, float& a3) {
    if constexpr (R <= REND) {
        tap<R>(p, a0, a1, a2, a3);
        sweep<R + 2, REND>(p, a0, a1, a2, a3);
    }
}

// ---------------------------------------------------------------------------
// Kernel 1: ramp filter — R5's proven structure, output pair-interleaved
// g_ft[g][a][d][2] (g = b>>1, j = b&1).
// ---------------------------------------------------------------------------
__global__ __launch_bounds__(256) void ramp_filter_kernel(
        const float* __restrict__ x) {
    const int a   = blockIdx.x;
    const int b   = blockIdx.y;
    const int tid = threadIdx.x;        // 0..255
    const int t    = tid & 127;         // output-thread id
    const int half = tid >> 7;          // window half
    const int q = (t & 31) + 128 * (t >> 5);   // base output (covers all 512)

    __shared__ float xs[3 * DET];       // [0,512) zeros | data | [1024,1536) zeros
    __shared__ float red[4 * 128];      // half-1 partial accumulators

    xs[tid]        = 0.0f;
    xs[256 + tid]  = 0.0f;
    xs[1024 + tid] = 0.0f;
    xs[1280 + tid] = 0.0f;
    xs[512 + tid]  = x[(b * DET + tid) * NA + a];
    xs[768 + tid]  = x[(b * DET + 256 + tid) * NA + a];
    __syncthreads();

    const float* p = xs + 512 + q;
    float a0 = 0.0f, a1 = 0.0f, a2 = 0.0f, a3 = 0.0f;

    if (half == 0) {
        a0 = 0.5f * p[0];               // center taps, once
        a1 = 0.5f * p[32];
        a2 = 0.5f * p[64];
        a3 = 0.5f * p[96];
        sweep<-511, 47>(p, a0, a1, a2, a3);
    } else {
        sweep<49, 607>(p, a0, a1, a2, a3);
        red[      t] = a0;
        red[128 + t] = a1;
        red[256 + t] = a2;
        red[384 + t] = a3;
    }
    __syncthreads();

    if (half == 0) {
        const int g = b >> 1, j = b & 1;
        float* o = g_ft + (((size_t)g * NA + a) * DET + q) * 2 + j;
        o[0]       = a0 + red[      t];
        o[32 * 2]  = a1 + red[128 + t];
        o[64 * 2]  = a2 + red[256 + t];
        o[96 * 2]  = a3 + red[384 + t];
    }
}

// ---------------------------------------------------------------------------
// Kernel 2: backprojection — R16 best-known-good (92.16 us total).
// Pair-fused (one ds_read2_b64-class access serves 2 images; index math
// shared) + T14 async-stage split (chunk rd+1's 3 float4 loaded into
// registers right after the LDS-write barrier, L2 latency hides under
// chunk rd's 12-interp compute).  32x32 tile, 4 px/thread, 256 threads,
// NSPLIT=6, CHUNK=3 (12.3 KB LDS).
// Measured neighborhood (all worse): dbuf 1-barrier/round +1.4; CHUNK=6
// +8.3; fused-4 b128/b32/no-LDS +5..+29; 16px tiles +26..+166.
// ---------------------------------------------------------------------------
__device__ __forceinline__ void interp2(float2& acc,
        const float* __restrict__ L, float pos) {
    float pf = floorf(pos);
    int   i0 = (int)pf;
    float fr = pos - pf;
    const float* qp = L + 2 * i0;
    float g00 = qp[0], g01 = qp[1];          // pair at d = i0
    float g10 = qp[2], g11 = qp[3];          // pair at d = i0+1
    float v0 = fmaf(fr, g10 - g00, g00);
    float v1 = fmaf(fr, g11 - g01, g01);
    bool in = pos <= (float)(DET - 1);       // fill=0 outside
    acc.x += in ? v0 : 0.0f;
    acc.y += in ? v1 : 0.0f;
}

__global__ __launch_bounds__(256) void backproject_kernel(
        float* __restrict__ out) {
    const int bz = blockIdx.z;
    const int g  = bz / NSPLIT;              // image pair 0..1
    const int sp = bz - g * NSPLIT;
    const int r0 = blockIdx.y * 32;
    const int c0 = blockIdx.x * 32;
    const int tid = threadIdx.x;
    const int tx = tid & 15;
    const int ty = tid >> 4;

    __shared__ float line[CHUNK * LSTR2];    // 3 pair-lines, 12.3 KB

    // zero sentinel pair at d=512 (dwords 1024,1025 of each line)
    if (tid < 2 * CHUNK)
        line[(tid >> 1) * LSTR2 + 1024 + (tid & 1)] = 0.0f;

    // clamp base coordinate for guard pixels (r/c >= OUT); stores guarded.
    const float xpr = (float)(min(r0 + ty, OUT - 1) - RAD);   // row coord
    const float ypr = (float)(min(c0 + tx, OUT - 1) - RAD);   // col coord

    float2 a00 = {0,0}, a01 = {0,0}, a10 = {0,0}, a11 = {0,0};

    const float4* base4 =
        (const float4*)(g_ft + ((size_t)g * NA + sp * APB) * DET * 2);

    // prologue: prefetch chunk 0 (3 quads/thread; quad j4 -> line j4>>8,
    // dword (j4&255)<<2; with j4 = tid + 256k this is line k, dword tid<<2)
    float4 pf0 = base4[tid];
    float4 pf1 = base4[tid + 256];
    float4 pf2 = base4[tid + 512];

    for (int rd = 0; rd < APB / CHUNK; ++rd) {
        __syncthreads();                     // previous chunk's compute done
        *(float4*)&line[0 * LSTR2 + (tid << 2)] = pf0;   // waits vmcnt here
        *(float4*)&line[1 * LSTR2 + (tid << 2)] = pf1;
        *(float4*)&line[2 * LSTR2 + (tid << 2)] = pf2;
        __syncthreads();

        // issue next chunk's loads NOW — latency hides under compute below
        if (rd + 1 < APB / CHUNK) {
            const float4* gn = base4 + (size_t)(rd + 1) * (CHUNK * DET * 2 / 4);
            pf0 = gn[tid];
            pf1 = gn[tid + 256];
            pf2 = gn[tid + 512];
        }

        const int abase = sp * APB + rd * CHUNK;
        #pragma unroll
        for (int i = 0; i < CHUNK; ++i) {
            const float cv = TRIG.c[abase + i];
            const float sv = TRIG.s[abase + i];
            // pos = ypr*cos - xpr*sin + det/2
            float p00 = fmaf(ypr, cv, fmaf(xpr, -sv, 256.0f));
            float p01 = fmaf(16.0f, cv, p00);       // col+16
            float p10 = fmaf(-16.0f, sv, p00);      // row+16
            float p11 = fmaf(-16.0f, sv, p01);      // row+16, col+16
            const float* L = line + i * LSTR2;
            interp2(a00, L, p00);
            interp2(a01, L, p01);
            interp2(a10, L, p10);
            interp2(a11, L, p11);
        }
    }

    const float scale = (float)(PI_D / (2.0 * NA));
    const int r = r0 + ty;
    const int c = c0 + tx;
    float* ob0 = out + (size_t)(2 * g)     * OUTSQ;
    float* ob1 = out + (size_t)(2 * g + 1) * OUTSQ;

#define EMIT(ACC, RR, CC)                                          \
    if ((RR) < OUT && (CC) < OUT) {                                \
        const int off = (RR) * OUT + (CC);                         \
        atomicAdd(ob0 + off, (ACC).x * scale);                     \
        atomicAdd(ob1 + off, (ACC).y * scale);                     \
    }
    EMIT(a00, r, c);
    EMIT(a01, r, c + 16);
    EMIT(a10, r + 16, c);
    EMIT(a11, r + 16, c + 16);
#undef EMIT
}

extern "C" void kernel_launch(void* const* d_in, const int* in_sizes, int n_in,
                              void* d_out, int out_size, void* d_ws, size_t ws_size,
                              hipStream_t stream) {
    const float* x = (const float*)d_in[0];
    float* out = (float*)d_out;

    const int B = in_sizes[0] / (DET * NA);   // 4 (fixed)
    (void)d_ws; (void)ws_size;                // workspace deliberately unused

    hipMemsetAsync(out, 0, (size_t)out_size * sizeof(float), stream);
    ramp_filter_kernel<<<dim3(NA, B), 256, 0, stream>>>(x);
    backproject_kernel<<<dim3((OUT + 31) / 32, (OUT + 31) / 32, (B / 2) * NSPLIT),
                         256, 0, stream>>>(out);
}